// Round 7
// baseline (105.340 us; speedup 1.0000x reference)
//
#include <hip/hip_runtime.h>
#include <hip/hip_bf16.h>

typedef __attribute__((ext_vector_type(4))) float f32x4;
typedef __attribute__((ext_vector_type(8))) short short8v;
typedef __attribute__((ext_vector_type(8))) unsigned short ushort8v;

#define T_ROWS 16384
#define H_DIM  4096
#define E_NUM  64
#define TOPK   8
#define MROWS  32               // rows per block
#define KC     128              // k-chunk
#define NCH    (H_DIM / KC)     // 32 chunks
#define WIMG   32768            // bytes per W chunk image (hi+lo planes)

__device__ __forceinline__ unsigned short f2bf(float f) {
    unsigned int u = __float_as_uint(f);
    unsigned int r = (u + 0x7fffu + ((u >> 16) & 1u)) >> 16;  // RNE
    return (unsigned short)r;
}
__device__ __forceinline__ float bf2f(unsigned short h) {
    return __uint_as_float(((unsigned int)h) << 16);
}
// swizzled byte offset inside a [rows][256B] tile
__device__ __forceinline__ int swz(int row, int bytecol) {
    return row * 256 + (bytecol ^ ((row & 7) << 4));
}
__device__ __forceinline__ void gload_lds16(const void* g, void* l) {
    __builtin_amdgcn_global_load_lds(
        (const __attribute__((address_space(1))) unsigned int*)g,
        (__attribute__((address_space(3))) unsigned int*)l, 16, 0, 0);
}

// ---- prep: build per-chunk swizzled LDS images of W (bf16 hi/lo) in d_ws ----
// layout: for ch in [0,32): 32KB = [plane hi|lo 16KB][row 0..63][256B swizzled]
__global__ __launch_bounds__(256) void prep_w(
    const float* __restrict__ W, unsigned short* __restrict__ WS)
{
    const int g     = blockIdx.x * 256 + threadIdx.x;   // one 16B group
    const int byteo = g * 16;
    const int ch    = byteo >> 15;
    const int rem   = byteo & 32767;
    const int plane = rem >> 14;
    const int rb2   = rem & 16383;
    const int row   = rb2 >> 8;
    const int sb    = rb2 & 255;
    const int bc    = sb ^ ((row & 7) << 4);
    const float* src = W + (size_t)row * H_DIM + ch * KC + (bc >> 1);
    ushort8v o;
#pragma unroll
    for (int j = 0; j < 8; ++j) {
        const float f = src[j];
        const unsigned short hb = f2bf(f);
        o[j] = (plane == 0) ? hb : f2bf(f - bf2f(hb));
    }
    *(ushort8v*)((char*)WS + byteo) = o;
}

// ---- main: 512 thr = 8 waves; wave (r=w&1, c=w>>1) = 16 rows x 16 experts ----
__global__ __launch_bounds__(512, 4) void router_main(
    const float* __restrict__ X, const unsigned short* __restrict__ WS,
    const int* __restrict__ ids, int nids, float* __restrict__ out)
{
    const int tid  = threadIdx.x;
    const int lane = tid & 63;
    const int w    = tid >> 6;        // 0..7
    const int r    = w & 1;           // row-tile
    const int c    = w >> 1;          // expert quarter
    const int rb   = blockIdx.x * MROWS;
    const int fr   = lane & 15;
    const int fq   = lane >> 4;

    __shared__ unsigned short XHs[MROWS * KC];     // 8 KB swizzled
    __shared__ unsigned short XLs[MROWS * KC];     // 8 KB
    __shared__ unsigned short WB[2][WIMG / 2];     // 2 x 32 KB, dbuf W images

    const int sxrow = tid >> 4;              // 0..31
    const int sxcol = (tid & 15) * 8;        // f32 elems
    const float* xg = X + (size_t)(rb + sxrow) * H_DIM + sxcol;
    const char*  wsg = (const char*)WS;

    f32x4 acc = {0.f, 0.f, 0.f, 0.f};

    // ---- prologue: W chunk0 -> WB[0] (DMA), X chunk0 -> regs -> split ----
    {
        char* wd = (char*)&WB[0][0];
#pragma unroll
        for (int i = 0; i < 4; ++i) {
            const int off = (w * 4 + i) * 1024;
            gload_lds16(wsg + off + lane * 16, wd + off);
        }
    }
    float4 px0 = *(const float4*)(xg);
    float4 px1 = *(const float4*)(xg + 4);
    ushort8v hv, lv;
    {
        float v[8] = {px0.x, px0.y, px0.z, px0.w, px1.x, px1.y, px1.z, px1.w};
#pragma unroll
        for (int j = 0; j < 8; ++j) {
            const unsigned short hb = f2bf(v[j]);
            hv[j] = hb;
            lv[j] = f2bf(v[j] - bf2f(hb));
        }
    }
    int cur = 0;

    for (int ch = 0; ch < NCH; ++ch) {
        __syncthreads();   // [A] prev compute done; drains in-flight W DMA + X loads
        // ---- stage window: just two b128 writes ----
        *(ushort8v*)((char*)XHs + swz(sxrow, sxcol * 2)) = hv;
        *(ushort8v*)((char*)XLs + swz(sxrow, sxcol * 2)) = lv;
        __syncthreads();   // [B] X tile ready; WB[cur] ready since [A]
        // ---- issue next chunk's W DMA + X register loads ----
        if (ch + 1 < NCH) {
            const char* wsn = wsg + (size_t)(ch + 1) * WIMG;
            char* wd = (char*)&WB[cur ^ 1][0];
#pragma unroll
            for (int i = 0; i < 4; ++i) {
                const int off = (w * 4 + i) * 1024;
                gload_lds16(wsn + off + lane * 16, wd + off);
            }
            px0 = *(const float4*)(xg + (ch + 1) * KC);
            px1 = *(const float4*)(xg + (ch + 1) * KC + 4);
        }
        // ---- compute: 4 k-steps x 3 MFMA (split-bf16) ----
        const char* wb = (const char*)&WB[cur][0];   // hi plane; lo at +16384
#pragma unroll
        for (int ks = 0; ks < KC / 32; ++ks) {
            const int bc = ks * 64 + fq * 16;
            short8v ah = *(const short8v*)((const char*)XHs + swz(r * 16 + fr, bc));
            short8v al = *(const short8v*)((const char*)XLs + swz(r * 16 + fr, bc));
            short8v bh = *(const short8v*)(wb + swz(c * 16 + fr, bc));
            short8v bl = *(const short8v*)(wb + 16384 + swz(c * 16 + fr, bc));
            acc = __builtin_amdgcn_mfma_f32_16x16x32_bf16(ah, bh, acc, 0, 0, 0);
            acc = __builtin_amdgcn_mfma_f32_16x16x32_bf16(ah, bl, acc, 0, 0, 0);
            acc = __builtin_amdgcn_mfma_f32_16x16x32_bf16(al, bh, acc, 0, 0, 0);
        }
        // ---- split next X (VALU; overlaps MFMA pipe) ----
        if (ch + 1 < NCH) {
            float v[8] = {px0.x, px0.y, px0.z, px0.w, px1.x, px1.y, px1.z, px1.w};
#pragma unroll
            for (int j = 0; j < 8; ++j) {
                const unsigned short hb = f2bf(v[j]);
                hv[j] = hb;
                lv[j] = f2bf(v[j] - bf2f(hb));
            }
        }
        cur ^= 1;
    }

    // ---- logits scoreboard in LDS (reuse W buffer), then epilogue ----
    __syncthreads();                       // all compute done
    float* sm = (float*)&WB[0][0];         // [32][68] = 8.7 KB << 64 KB
#pragma unroll
    for (int j = 0; j < 4; ++j) {
        const int row_l = r * 16 + fq * 4 + j;
        sm[row_l * 68 + c * 16 + fr] = acc[j];
    }
    __syncthreads();
    if (w >= 2) return;                    // no barriers after this point

    // allowed-expert bitmask (uniform; scalar-cached)
    unsigned long long mbits = 0;
    for (int t = 0; t < nids; ++t) {
        const int e = ids[t];
        if (e >= 0 && e < E_NUM) mbits |= (1ull << e);
    }

    float* o_log = out;
    float* o_rw  = out + (size_t)T_ROWS * E_NUM;
    float* o_se  = o_rw + (size_t)T_ROWS * TOPK;

#pragma unroll
    for (int j = 0; j < 4; ++j) {
        const int row_l = r * 16 + fq * 4 + j;
        const int grow  = rb + row_l;
        float a0 = sm[row_l * 68 +  0 + fr];
        float a1 = sm[row_l * 68 + 16 + fr];
        float a2 = sm[row_l * 68 + 32 + fr];
        float a3 = sm[row_l * 68 + 48 + fr];
        float mv0 = ((mbits >> ( 0 + fr)) & 1) ? a0 : -10000.0f;
        float mv1 = ((mbits >> (16 + fr)) & 1) ? a1 : -10000.0f;
        float mv2 = ((mbits >> (32 + fr)) & 1) ? a2 : -10000.0f;
        float mv3 = ((mbits >> (48 + fr)) & 1) ? a3 : -10000.0f;
        o_log[(size_t)grow * 64 +  0 + fr] = mv0;
        o_log[(size_t)grow * 64 + 16 + fr] = mv1;
        o_log[(size_t)grow * 64 + 32 + fr] = mv2;
        o_log[(size_t)grow * 64 + 48 + fr] = mv3;

        float m = fmaxf(fmaxf(mv0, mv1), fmaxf(mv2, mv3));
#pragma unroll
        for (int off = 1; off < 16; off <<= 1) m = fmaxf(m, __shfl_xor(m, off));

        float tsum = 0.f, myv = 0.f;
        int   mye  = 0;
#pragma unroll
        for (int t = 0; t < TOPK; ++t) {
            float bv = mv0; int be = fr;
            if (mv1 > bv) { bv = mv1; be = 16 + fr; }
            if (mv2 > bv) { bv = mv2; be = 32 + fr; }
            if (mv3 > bv) { bv = mv3; be = 48 + fr; }
#pragma unroll
            for (int off = 1; off < 16; off <<= 1) {
                float ov = __shfl_xor(bv, off);
                int   oe = __shfl_xor(be, off);
                if (ov > bv || (ov == bv && oe < be)) { bv = ov; be = oe; }
            }
            const float pv = expf(bv - m);
            tsum += pv;
            if (fr == t) { myv = pv; mye = be; }
            if ((be & 15) == fr) {       // owner lane excludes winner
                const int bn = be >> 4;
                if      (bn == 0) mv0 = -3.4e38f;
                else if (bn == 1) mv1 = -3.4e38f;
                else if (bn == 2) mv2 = -3.4e38f;
                else              mv3 = -3.4e38f;
            }
        }
        if (fr < TOPK) {
            o_rw[(size_t)grow * TOPK + fr] = myv / tsum;
            o_se[(size_t)grow * TOPK + fr] = (float)mye;
        }
    }
}

extern "C" void kernel_launch(void* const* d_in, const int* in_sizes, int n_in,
                              void* d_out, int out_size, void* d_ws, size_t ws_size,
                              hipStream_t stream) {
    const float* X   = (const float*)d_in[0];
    const float* W   = (const float*)d_in[1];
    const int*   ids = (const int*)d_in[2];
    const int    nids = in_sizes[2];
    float* out = (float*)d_out;

    unsigned short* WS = (unsigned short*)d_ws;   // 1 MB swizzled W image

    hipLaunchKernelGGL(prep_w, dim3(NCH * WIMG / 16 / 256), dim3(256), 0, stream, W, WS);
    hipLaunchKernelGGL(router_main, dim3(T_ROWS / MROWS), dim3(512), 0, stream,
                       X, WS, ids, nids, out);
}